// Round 1
// baseline (12532.558 us; speedup 1.0000x reference)
//
#include <hip/hip_runtime.h>
#include <hip/hip_cooperative_groups.h>

namespace cg = cooperative_groups;

#define S_LEN 256
// ws offsets (in floats)
#define XT_OFF   0            // [256][512][32]  inputs transposed per step
#define ROT_OFF  4194304      // [256][256][32]  read_outs transposed (m-major)
#define HT_OFF   6291456      // [2][512][32]    h double-buffered, [d][n]
#define H2_OFF   6324224      // [2][32][768]    har rows: h(512) ++ ro(256)
#define CT_OFF   6373376      // [512][32]       c state, [d][n]
#define WAT_OFF  6389760      // [40][768]
#define WQT_OFF  6420480      // [256][768]
#define WVT_OFF  6617088      // [256][512]
#define WKT_OFF  6748160      // [256][512]
#define WS_TOTAL 6879232      // floats (~26.2 MB)

__global__ __launch_bounds__(256) void k_transpose_x(const float* __restrict__ in, float* __restrict__ xT) {
  int idx = blockIdx.x * 256 + threadIdx.x;            // output-ordered
  int s = idx >> 14, r = idx & 16383, k = r >> 5, n = r & 31;
  xT[idx] = in[(s << 14) + (n << 9) + k];
}

__global__ __launch_bounds__(256) void k_transpose_w(const float* __restrict__ src, float* __restrict__ dst,
                                                     int K, int C) {
  int c = blockIdx.x;
  int k = blockIdx.y * 256 + threadIdx.x;
  dst[c * K + k] = src[k * C + c];
}

struct P1S { float red[256][33]; float sg[512]; };
struct DS {
  float tape[32][64]; float tkey[32][64];
  float rpos[32]; float wpos[32];
  float har[768]; float xrow[512];
  float act[12]; float q[64]; float v[64]; float kr[64];
  float dv[64]; float dk[64]; float ro[64];
  float scrA[256]; float scrB[256];
  float norm;
};
union SU { P1S p; DS d; };

__global__ __launch_bounds__(256) void nam_coop(
    const float* __restrict__ inp, const float* __restrict__ Wih, const float* __restrict__ Whh,
    const float* __restrict__ bih, const float* __restrict__ bhh,
    const float* __restrict__ ba, const float* __restrict__ bq,
    const float* __restrict__ bv, const float* __restrict__ bk,
    float* __restrict__ ws, float* __restrict__ out)
{
  cg::grid_group grid = cg::this_grid();
  __shared__ SU sm;
  const int blk = blockIdx.x, tid = threadIdx.x;
  const bool isP1 = (blk < 128);

  if (!isP1) {
    for (int i = tid; i < 2048; i += 256) { int l = i >> 6, c = i & 63; sm.d.tape[l][c] = 0.f; sm.d.tkey[l][c] = 0.f; }
    if (tid < 32) { sm.d.rpos[tid] = (tid == 0) ? 1.f : 0.f; sm.d.wpos[tid] = (tid == 0) ? 1.f : 0.f; }
    __syncthreads();
  }

  for (int t = 0; t <= S_LEN; ++t) {
    if (isP1) {
      if (t < S_LEN) {
        // ---- LSTM step t: gates = x_t@Wih + h_{t-1}@Whh + biases; update c,h ----
        const int dd = tid & 3, g4 = (tid >> 2) & 3, ks = tid >> 4;  // ks 0..15
        const int col = g4 * 512 + blk * 4 + dd;
        const float* Abase; const float* Wbase;
        if (ks < 8) { Abase = ws + XT_OFF + t * 16384 + ks * 2048; Wbase = Wih + (ks * 64) * 2048 + col; }
        else        { Abase = ws + HT_OFF + ((t + 1) & 1) * 16384 + (ks - 8) * 2048; Wbase = Whh + ((ks - 8) * 64) * 2048 + col; }
        float acc[32];
#pragma unroll
        for (int n2 = 0; n2 < 32; ++n2) acc[n2] = 0.f;
        float4 av[8]; float wv;
        {
          const float4* Ap = (const float4*)Abase;
#pragma unroll
          for (int j = 0; j < 8; ++j) av[j] = Ap[j];
          wv = Wbase[0];
        }
        for (int kk = 0; kk < 64; ++kk) {
          float4 nv[8]; float nw = 0.f;
          if (kk < 63) {
            const float4* An = (const float4*)(Abase + (kk + 1) * 32);
#pragma unroll
            for (int j = 0; j < 8; ++j) nv[j] = An[j];
            nw = Wbase[(kk + 1) * 2048];
          }
#pragma unroll
          for (int j = 0; j < 8; ++j) {
            acc[4 * j + 0] = fmaf(av[j].x, wv, acc[4 * j + 0]);
            acc[4 * j + 1] = fmaf(av[j].y, wv, acc[4 * j + 1]);
            acc[4 * j + 2] = fmaf(av[j].z, wv, acc[4 * j + 2]);
            acc[4 * j + 3] = fmaf(av[j].w, wv, acc[4 * j + 3]);
          }
          if (kk < 63) {
#pragma unroll
            for (int j = 0; j < 8; ++j) av[j] = nv[j];
            wv = nw;
          }
        }
#pragma unroll
        for (int n2 = 0; n2 < 32; ++n2) sm.p.red[tid][n2] = acc[n2];
        __syncthreads();
        for (int cell = tid; cell < 512; cell += 256) {
          int n2 = cell >> 4, cp = cell & 15;
          float sum = 0.f;
#pragma unroll
          for (int ks2 = 0; ks2 < 16; ++ks2) sum += sm.p.red[ks2 * 16 + cp][n2];
          int colc = (cp >> 2) * 512 + blk * 4 + (cp & 3);
          sm.p.sg[n2 * 16 + cp] = sum + bih[colc] + bhh[colc];
        }
        __syncthreads();
        if (tid < 128) {
          int n2 = tid >> 2, dd2 = tid & 3;
          const float* g = &sm.p.sg[n2 * 16];
          float gi = g[dd2], gf = g[4 + dd2], gg = g[8 + dd2], go = g[12 + dd2];
          float si = 1.f / (1.f + expf(-gi));
          float sf = 1.f / (1.f + expf(-gf));
          float so = 1.f / (1.f + expf(-go));
          int d = blk * 4 + dd2;
          float cc = ws[CT_OFF + d * 32 + n2];
          float cn = sf * cc + si * tanhf(gg);
          float hn = so * tanhf(cn);
          ws[CT_OFF + d * 32 + n2] = cn;
          ws[HT_OFF + (t & 1) * 16384 + d * 32 + n2] = hn;
          ws[H2_OFF + (t & 1) * 24576 + n2 * 768 + d] = hn;
        }
      }
    } else {
      if (t >= 1) {
        // ---- tape step tau = t-1 for group (n, tp) ----
        const int tau = t - 1;
        const int gidx = blk - 128, n = gidx >> 2, tp = gidx & 3;
        {
          const float* hrow = ws + H2_OFF + (tau & 1) * 24576 + n * 768;
          sm.d.har[tid] = hrow[tid];
          sm.d.har[tid + 256] = hrow[tid + 256];
          sm.d.har[tid + 512] = hrow[tid + 512];
          const float* xr = inp + tau * 16384 + n * 512;
          sm.d.xrow[tid] = xr[tid];
          sm.d.xrow[tid + 256] = xr[tid + 256];
        }
        __syncthreads();
        // action (10) + query (64), K=768, 3-way K-split
        if (tid < 222) {
          int o = tid % 74, ks2 = tid / 74;
          const float* wt = (o < 10) ? (ws + WAT_OFF + (tp * 10 + o) * 768)
                                     : (ws + WQT_OFF + (tp * 64 + (o - 10)) * 768);
          const float4* w4 = (const float4*)(wt + ks2 * 256);
          const float4* h4 = (const float4*)(sm.d.har + ks2 * 256);
          float p = 0.f;
#pragma unroll 8
          for (int j = 0; j < 64; ++j) {
            float4 a = w4[j], b = h4[j];
            p += a.x * b.x + a.y * b.y + a.z * b.z + a.w * b.w;
          }
          sm.d.scrA[tid] = p;
        }
        __syncthreads();
        if (tid < 74) {
          float val = sm.d.scrA[tid] + sm.d.scrA[tid + 74] + sm.d.scrA[tid + 148];
          if (tid < 10) sm.d.act[tid] = val + ba[tp * 10 + tid];
          else          sm.d.q[tid - 10] = val + bq[tp * 64 + tid - 10];
        }
        __syncthreads();
        float rd0, rd1, rd2, rd3, wd0, wd1, wd2, wd3, rw0, rw1;
        {
          float a0 = sm.d.act[0], a1 = sm.d.act[1], a2 = sm.d.act[2], a3 = sm.d.act[3];
          float mx = fmaxf(fmaxf(a0, a1), fmaxf(a2, a3));
          float e0 = expf(a0 - mx), e1 = expf(a1 - mx), e2 = expf(a2 - mx), e3 = expf(a3 - mx);
          float inv = 1.f / (e0 + e1 + e2 + e3);
          rd0 = e0 * inv; rd1 = e1 * inv; rd2 = e2 * inv; rd3 = e3 * inv;
          a0 = sm.d.act[4]; a1 = sm.d.act[5]; a2 = sm.d.act[6]; a3 = sm.d.act[7];
          mx = fmaxf(fmaxf(a0, a1), fmaxf(a2, a3));
          e0 = expf(a0 - mx); e1 = expf(a1 - mx); e2 = expf(a2 - mx); e3 = expf(a3 - mx);
          inv = 1.f / (e0 + e1 + e2 + e3);
          wd0 = e0 * inv; wd1 = e1 * inv; wd2 = e2 * inv; wd3 = e3 * inv;
          rw0 = 1.f / (1.f + expf(-sm.d.act[8]));
          rw1 = 1.f / (1.f + expf(-sm.d.act[9]));
        }
        // v / k_raw, K=512, 2-way K-split
        {
          int o = tid & 127, k2 = tid >> 7;
          const float* wt = (o < 64) ? (ws + WVT_OFF + (tp * 64 + o) * 512)
                                     : (ws + WKT_OFF + (tp * 64 + (o - 64)) * 512);
          const float4* w4 = (const float4*)(wt + k2 * 256);
          const float4* x4 = (const float4*)(sm.d.xrow + k2 * 256);
          float p = 0.f;
#pragma unroll 8
          for (int j = 0; j < 64; ++j) {
            float4 a = w4[j], b = x4[j];
            p += a.x * b.x + a.y * b.y + a.z * b.z + a.w * b.w;
          }
          sm.d.scrB[tid] = p;
        }
        __syncthreads();
        if (tid < 128) {
          float val = sm.d.scrB[tid] + sm.d.scrB[tid + 128];
          if (tid < 64) sm.d.v[tid] = val + bv[tp * 64 + tid];
          else          sm.d.kr[tid - 64] = val + bk[tp * 64 + tid - 64];
        }
        __syncthreads();
        if (tid < 64) {
          float x = sm.d.kr[tid];
          float ss = x * x;
#pragma unroll
          for (int off = 32; off > 0; off >>= 1) ss += __shfl_down(ss, off, 64);
          if (tid == 0) sm.d.norm = fmaxf(sqrtf(ss), 1e-12f);
        }
        __syncthreads();
        if (tid < 64) sm.d.kr[tid] = sm.d.kr[tid] / sm.d.norm;
        __syncthreads();
        const int c = tid & 63, ls = tid >> 6;
        {
          float pv = 0.f, pk = 0.f;
#pragma unroll
          for (int i = 0; i < 8; ++i) {
            int l = ls * 8 + i;
            float wp = sm.d.wpos[l];
            pv = fmaf(sm.d.tape[l][c], wp, pv);
            pk = fmaf(sm.d.tkey[l][c], wp, pk);
          }
          sm.d.scrA[tid] = pv; sm.d.scrB[tid] = pk;
        }
        __syncthreads();
        if (tid < 64) {
          float ov = sm.d.scrA[tid] + sm.d.scrA[tid + 64] + sm.d.scrA[tid + 128] + sm.d.scrA[tid + 192];
          float ok = sm.d.scrB[tid] + sm.d.scrB[tid + 64] + sm.d.scrB[tid + 128] + sm.d.scrB[tid + 192];
          sm.d.dv[tid] = (sm.d.v[tid] - ov) * rw1;
          sm.d.dk[tid] = (sm.d.kr[tid] - ok) * rw1;
        }
        __syncthreads();
        {
          float pr = 0.f;
          float dvc = sm.d.dv[c], dkc = sm.d.dk[c];
#pragma unroll
          for (int i = 0; i < 8; ++i) {
            int l = ls * 8 + i;
            float wp = sm.d.wpos[l];
            float tv = sm.d.tape[l][c] + wp * dvc;
            sm.d.tape[l][c] = tv;
            sm.d.tkey[l][c] += wp * dkc;
            pr = fmaf(tv, sm.d.rpos[l], pr);
          }
          sm.d.scrA[tid] = pr;
        }
        __syncthreads();
        if (tid < 64) {
          float r = sm.d.scrA[tid] + sm.d.scrA[tid + 64] + sm.d.scrA[tid + 128] + sm.d.scrA[tid + 192];
          sm.d.ro[tid] = r * rw0;
        }
        __syncthreads();
        {
          int l2 = tid & 31, cs = tid >> 5;
          float pj = 0.f;
#pragma unroll
          for (int i = 0; i < 8; ++i) {
            int cc = cs * 8 + i;
            pj = fmaf(sm.d.tkey[l2][cc], sm.d.q[cc], pj);
          }
          sm.d.scrB[tid] = pj;
        }
        __syncthreads();
        float jp = 0.f;
        if (tid < 32) {
#pragma unroll
          for (int cs2 = 0; cs2 < 8; ++cs2) jp += sm.d.scrB[cs2 * 32 + tid];
        }
        if (tid < 64) {
          float v2 = (tid < 32) ? jp : 0.f;
          float ss = v2 * v2;
#pragma unroll
          for (int off = 32; off > 0; off >>= 1) ss += __shfl_down(ss, off, 64);
          if (tid == 0) sm.d.norm = fmaxf(sqrtf(ss), 1e-12f);
        }
        __syncthreads();
        if (tid < 32) {
          float jn = jp / sm.d.norm;
          float prv = sm.d.rpos[(tid + 1) & 31];   // roll(rpos,-1)
          float nxt = sm.d.rpos[(tid + 31) & 31];  // roll(rpos,+1)
          float rp = sm.d.rpos[tid], wp = sm.d.wpos[tid];
          float wnew = prv * wd0 + wp * wd1 + nxt * wd2 + jn * wd3;
          float rnew = prv * rd0 + rp * rd1 + nxt * rd2 + jn * rd3;
          sm.d.wpos[tid] = wnew;
          sm.d.rpos[tid] = rnew;
        }
        if (tid < 64) {
          float rov = sm.d.ro[tid];
          ws[H2_OFF + ((tau + 1) & 1) * 24576 + n * 768 + 512 + tp * 64 + tid] = rov;
          ws[ROT_OFF + tau * 8192 + (tp * 64 + tid) * 32 + n] = rov;
        }
        if (tau == S_LEN - 1) {
          __syncthreads();
          for (int i = tid; i < 2048; i += 256) {
            int l = i >> 6, cc = i & 63;
            out[4194304 + (l * 32 + n) * 256 + tp * 64 + cc] = sm.d.tape[l][cc];
          }
        }
      }
    }
    grid.sync();
  }
}

__global__ __launch_bounds__(256) void k_out_gemm(const float* __restrict__ roT, const float* __restrict__ Wo,
                                                  const float* __restrict__ bo, float* __restrict__ out) {
  int s = blockIdx.x >> 1, dh = blockIdx.x & 1;
  int d = dh * 256 + threadIdx.x;
  const float* rb = roT + s * 8192;
  float acc[32];
#pragma unroll
  for (int n = 0; n < 32; ++n) acc[n] = 0.f;
  for (int m = 0; m < 256; ++m) {
    float w = Wo[m * 512 + d];
    const float4* rc = (const float4*)(rb + m * 32);
#pragma unroll
    for (int j = 0; j < 8; ++j) {
      float4 r4 = rc[j];
      acc[4 * j + 0] = fmaf(r4.x, w, acc[4 * j + 0]);
      acc[4 * j + 1] = fmaf(r4.y, w, acc[4 * j + 1]);
      acc[4 * j + 2] = fmaf(r4.z, w, acc[4 * j + 2]);
      acc[4 * j + 3] = fmaf(r4.w, w, acc[4 * j + 3]);
    }
  }
  float bd = bo[d];
#pragma unroll
  for (int n = 0; n < 32; ++n) out[(s * 32 + n) * 512 + d] = acc[n] + bd;
}

extern "C" void kernel_launch(void* const* d_in, const int* in_sizes, int n_in,
                              void* d_out, int out_size, void* d_ws, size_t ws_size,
                              hipStream_t stream) {
  const float* inp = (const float*)d_in[0];
  const float* Wih = (const float*)d_in[1];
  const float* Whh = (const float*)d_in[2];
  const float* bih = (const float*)d_in[3];
  const float* bhh = (const float*)d_in[4];
  const float* Wa  = (const float*)d_in[5];
  const float* ba  = (const float*)d_in[6];
  const float* Wv  = (const float*)d_in[7];
  const float* bv  = (const float*)d_in[8];
  const float* Wk  = (const float*)d_in[9];
  const float* bk  = (const float*)d_in[10];
  const float* Wq  = (const float*)d_in[11];
  const float* bq  = (const float*)d_in[12];
  const float* Wo  = (const float*)d_in[13];
  const float* bo  = (const float*)d_in[14];
  float* ws = (float*)d_ws;
  float* out = (float*)d_out;

  // zero h/h2/c state (ws is re-poisoned before every launch)
  hipMemsetAsync(ws + HT_OFF, 0, (size_t)(32768 + 49152 + 16384) * sizeof(float), stream);
  k_transpose_x<<<16384, 256, 0, stream>>>(inp, ws + XT_OFF);
  k_transpose_w<<<dim3(40, 3), 256, 0, stream>>>(Wa, ws + WAT_OFF, 768, 40);
  k_transpose_w<<<dim3(256, 3), 256, 0, stream>>>(Wq, ws + WQT_OFF, 768, 256);
  k_transpose_w<<<dim3(256, 2), 256, 0, stream>>>(Wv, ws + WVT_OFF, 512, 256);
  k_transpose_w<<<dim3(256, 2), 256, 0, stream>>>(Wk, ws + WKT_OFF, 512, 256);

  void* args[] = { (void*)&inp, (void*)&Wih, (void*)&Whh, (void*)&bih, (void*)&bhh,
                   (void*)&ba, (void*)&bq, (void*)&bv, (void*)&bk, (void*)&ws, (void*)&out };
  hipLaunchCooperativeKernel((void*)nam_coop, dim3(256), dim3(256), args, 0, stream);

  k_out_gemm<<<512, 256, 0, stream>>>(ws + ROT_OFF, Wo, bo, out);
}

// Round 2
// 11059.908 us; speedup vs baseline: 1.1332x; 1.1332x over previous
//
#include <hip/hip_runtime.h>
#include <hip/hip_cooperative_groups.h>

namespace cg = cooperative_groups;

#define S_LEN 256
// ws float offsets
#define GI_OFF   0u           // [256][2048][32]  x@Wih + bih + bhh, [s][col][n]
#define VAL_OFF  16777216u    // [256][32][256]   x@Wv + bv
#define KEY_OFF  18874368u    // [256][32][256]   unitnorm(x@Wk + bk)
#define ROT_OFF  20971520u    // [256][256][32]   read_outs transposed
#define HT_OFF   23068672u    // [2][512][32]     h double-buffered, [d][n]
#define H2_OFF   23101440u    // [2][32][768]     har rows: h(512) ++ ro(256)
#define WAT_OFF  23150592u    // [40][768]
#define WQT_OFF  23181312u    // [256][768]
#define WS_TOTAL 23377920u    // ~93.5 MB

__global__ __launch_bounds__(256) void k_transpose_w(const float* __restrict__ src, float* __restrict__ dst,
                                                     int K, int C) {
  int c = blockIdx.x;
  int k = blockIdx.y * 256 + threadIdx.x;
  dst[c * K + k] = src[k * C + c];
}

// ---- parallel pre-pass: gi = x@Wih + bih + bhh ; values = x@Wv+bv ; keys_raw = x@Wk+bk ----
__global__ __launch_bounds__(256) void k_pre(const float* __restrict__ inp,
    const float* __restrict__ Wih, const float* __restrict__ bih, const float* __restrict__ bhh,
    const float* __restrict__ Wv, const float* __restrict__ bv,
    const float* __restrict__ Wk, const float* __restrict__ bk, float* __restrict__ ws)
{
  __shared__ __align__(16) float xs[256 * 32];   // 32 KB, chunk of x transposed [k][n], chunk-rotated
  const int s = blockIdx.x / 10, tile = blockIdx.x % 10;
  const int tid = threadIdx.x;
  const float* W; int C, c;
  if (tile < 8)       { W = Wih; C = 2048; c = tile * 256 + tid; }
  else if (tile == 8) { W = Wv;  C = 256;  c = tid; }
  else                { W = Wk;  C = 256;  c = tid; }

  float acc[32];
#pragma unroll
  for (int n = 0; n < 32; ++n) acc[n] = 0.f;

  for (int p = 0; p < 2; ++p) {
    __syncthreads();
    // stage x[s][n][p*256+k] -> xs[k][rot], coalesced global reads, 8-way-conflict LDS writes
    for (int w = 0; w < 32; ++w) {
      int i = tid + w * 256;              // 8192 floats
      int k = i & 255, n = i >> 8;
      float v = inp[s * 16384 + n * 512 + p * 256 + k];
      int pos = ((((n >> 2) + (k & 7)) & 7) << 2) | (n & 3);
      xs[k * 32 + pos] = v;
    }
    __syncthreads();
    const float* Wp = W + (size_t)(p * 256) * C + c;
#pragma unroll 8
    for (int kk = 0; kk < 256; ++kk) {
      float wv = Wp[(size_t)kk * C];
      const float4* row = (const float4*)(xs + kk * 32);
#pragma unroll
      for (int j = 0; j < 8; ++j) {
        float4 a = row[(j + (kk & 7)) & 7];
        acc[4 * j + 0] = fmaf(a.x, wv, acc[4 * j + 0]);
        acc[4 * j + 1] = fmaf(a.y, wv, acc[4 * j + 1]);
        acc[4 * j + 2] = fmaf(a.z, wv, acc[4 * j + 2]);
        acc[4 * j + 3] = fmaf(a.w, wv, acc[4 * j + 3]);
      }
    }
  }

  if (tile < 8) {
    float bb = bih[c] + bhh[c];
    float4* dst = (float4*)(ws + GI_OFF + (size_t)s * 65536 + (size_t)c * 32);
#pragma unroll
    for (int j = 0; j < 8; ++j)
      dst[j] = make_float4(acc[4 * j] + bb, acc[4 * j + 1] + bb, acc[4 * j + 2] + bb, acc[4 * j + 3] + bb);
  } else {
    unsigned base = (tile == 8) ? VAL_OFF : KEY_OFF;
    float bb = (tile == 8) ? bv[c] : bk[c];
#pragma unroll
    for (int n = 0; n < 32; ++n)
      ws[base + (size_t)s * 8192 + n * 256 + c] = acc[n] + bb;
  }
}

__global__ __launch_bounds__(256) void k_knorm(float* __restrict__ ws) {
  int b = blockIdx.x;               // s*32+n
  int m = threadIdx.x;
  float* p = ws + KEY_OFF + (size_t)b * 256;
  float x = p[m];
  float ss = x * x;
#pragma unroll
  for (int off = 32; off > 0; off >>= 1) ss += __shfl_xor(ss, off, 64);
  p[m] = x / fmaxf(sqrtf(ss), 1e-12f);
}

struct P1S { float hs[256 * 32]; float sg[16][33]; };
struct DS {
  float tape[32][64]; float tkey[32][64];
  float rpos[32]; float wpos[32];
  float har[768];
  float act[12]; float q[64]; float v[64]; float kr[64];
  float dv[64]; float dk[64]; float ro[64];
  float scrA[256]; float scrB[256];
  float norm;
};
union __align__(16) SU { P1S p; DS d; };

__global__ __launch_bounds__(256) void nam_coop(
    const float* __restrict__ Whh, const float* __restrict__ ba, const float* __restrict__ bq,
    float* __restrict__ ws, float* __restrict__ out)
{
  cg::grid_group grid = cg::this_grid();
  __shared__ SU sm;
  const int blk = blockIdx.x, tid = threadIdx.x;
  const bool isP1 = (blk < 128);

  // ---- persistent-RNN preload: each LSTM thread owns 32 Whh weights in VGPRs ----
  const int ks = tid & 15, cs = tid >> 4;          // k-split 16-way, 16 cols/block
  const int dd = cs & 3, g4 = cs >> 2;
  const int col = g4 * 512 + blk * 4 + dd;
  float w[32];
  float creg = 0.f;                                 // c state for (d,n) pair, tid<128
  const int dfin = tid >> 5, nfin = tid & 31;
  if (isP1) {
#pragma unroll
    for (int kk2 = 0; kk2 < 32; ++kk2) {
      int k = (kk2 >> 4) * 256 + (kk2 & 15) * 16 + ks;
      w[kk2] = Whh[(size_t)k * 2048 + col];
    }
  } else {
    for (int i = tid; i < 2048; i += 256) { int l = i >> 6, c = i & 63; sm.d.tape[l][c] = 0.f; sm.d.tkey[l][c] = 0.f; }
    if (tid < 32) { sm.d.rpos[tid] = (tid == 0) ? 1.f : 0.f; sm.d.wpos[tid] = (tid == 0) ? 1.f : 0.f; }
    __syncthreads();
  }

  for (int t = 0; t <= S_LEN; ++t) {
    if (isP1) {
      if (t < S_LEN) {
        // prefetch gi (x-part + biases) for this thread's (d,n) cell
        float gic[4] = {0.f, 0.f, 0.f, 0.f};
        if (tid < 128) {
#pragma unroll
          for (int g = 0; g < 4; ++g)
            gic[g] = ws[GI_OFF + (size_t)t * 65536 + (size_t)(g * 512 + blk * 4 + dfin) * 32 + nfin];
        }
        float acc[32];
#pragma unroll
        for (int n = 0; n < 32; ++n) acc[n] = 0.f;
        const float* hsrc = ws + HT_OFF + ((t + 1) & 1) * 16384;
        for (int p = 0; p < 2; ++p) {
          __syncthreads();
          // stage 256 rows of h [k][n] into LDS, XOR-swizzled 16B chunks
          const float4* src = (const float4*)(hsrc + p * 8192);
          float4* dst = (float4*)sm.p.hs;
#pragma unroll
          for (int w4i = 0; w4i < 8; ++w4i) {
            int i4 = tid + w4i * 256;
            int r = i4 >> 3, j = i4 & 7;
            dst[r * 8 + (j ^ (r & 7))] = src[i4];
          }
          __syncthreads();
#pragma unroll
          for (int kk = 0; kk < 16; ++kk) {
            int r = kk * 16 + ks;
            float wv = w[p * 16 + kk];
            const float4* row = (const float4*)sm.p.hs + r * 8;
#pragma unroll
            for (int j = 0; j < 8; ++j) {
              float4 a = row[j ^ (r & 7)];
              acc[4 * j + 0] = fmaf(a.x, wv, acc[4 * j + 0]);
              acc[4 * j + 1] = fmaf(a.y, wv, acc[4 * j + 1]);
              acc[4 * j + 2] = fmaf(a.z, wv, acc[4 * j + 2]);
              acc[4 * j + 3] = fmaf(a.w, wv, acc[4 * j + 3]);
            }
          }
        }
        // k-split reduction: 4 shuffles within each 16-lane group
#pragma unroll
        for (int n = 0; n < 32; ++n) {
          float v = acc[n];
          v += __shfl_down(v, 8, 16);
          v += __shfl_down(v, 4, 16);
          v += __shfl_down(v, 2, 16);
          v += __shfl_down(v, 1, 16);
          acc[n] = v;
        }
        if (ks == 0) {
#pragma unroll
          for (int n = 0; n < 32; ++n) sm.p.sg[cs][n] = acc[n];
        }
        __syncthreads();
        if (tid < 128) {
          float gv[4];
#pragma unroll
          for (int g = 0; g < 4; ++g) gv[g] = sm.p.sg[g * 4 + dfin][nfin] + gic[g];
          float si = 1.f / (1.f + expf(-gv[0]));
          float sf = 1.f / (1.f + expf(-gv[1]));
          float so = 1.f / (1.f + expf(-gv[3]));
          float cn = sf * creg + si * tanhf(gv[2]);
          float hn = so * tanhf(cn);
          creg = cn;
          int dg = blk * 4 + dfin;
          ws[HT_OFF + (t & 1) * 16384 + dg * 32 + nfin] = hn;
          ws[H2_OFF + (t & 1) * 24576 + nfin * 768 + dg] = hn;
        }
      }
    } else {
      if (t >= 1) {
        const int tau = t - 1;
        const int gidx = blk - 128, n = gidx >> 2, tp = gidx & 2 ? (gidx & 3) : (gidx & 3);
        const int tpp = gidx & 3;
        (void)tp;
        // stage har (768) + precomputed v/kr (64+64)
        {
          const float* hrow = ws + H2_OFF + (tau & 1) * 24576 + n * 768;
          if (tid < 192) ((float4*)sm.d.har)[tid] = ((const float4*)hrow)[tid];
          if (tid < 64)       sm.d.v[tid]       = ws[VAL_OFF + (size_t)tau * 8192 + n * 256 + tpp * 64 + tid];
          else if (tid < 128) sm.d.kr[tid - 64] = ws[KEY_OFF + (size_t)tau * 8192 + n * 256 + tpp * 64 + (tid - 64)];
        }
        __syncthreads();
        // action (10) + query (64), K=768, 3-way K-split
        if (tid < 222) {
          int o = tid % 74, ks2 = tid / 74;
          const float* wt = (o < 10) ? (ws + WAT_OFF + (tpp * 10 + o) * 768)
                                     : (ws + WQT_OFF + (tpp * 64 + (o - 10)) * 768);
          const float4* w4 = (const float4*)(wt + ks2 * 256);
          const float4* h4 = (const float4*)(sm.d.har + ks2 * 256);
          float p = 0.f;
#pragma unroll 16
          for (int j = 0; j < 64; ++j) {
            float4 a = w4[j], b = h4[j];
            p += a.x * b.x + a.y * b.y + a.z * b.z + a.w * b.w;
          }
          sm.d.scrA[tid] = p;
        }
        __syncthreads();
        if (tid < 74) {
          float val = sm.d.scrA[tid] + sm.d.scrA[tid + 74] + sm.d.scrA[tid + 148];
          if (tid < 10) sm.d.act[tid] = val + ba[tpp * 10 + tid];
          else          sm.d.q[tid - 10] = val + bq[tpp * 64 + tid - 10];
        }
        __syncthreads();
        float rd0, rd1, rd2, rd3, wd0, wd1, wd2, wd3, rw0, rw1;
        {
          float a0 = sm.d.act[0], a1 = sm.d.act[1], a2 = sm.d.act[2], a3 = sm.d.act[3];
          float mx = fmaxf(fmaxf(a0, a1), fmaxf(a2, a3));
          float e0 = expf(a0 - mx), e1 = expf(a1 - mx), e2 = expf(a2 - mx), e3 = expf(a3 - mx);
          float inv = 1.f / (e0 + e1 + e2 + e3);
          rd0 = e0 * inv; rd1 = e1 * inv; rd2 = e2 * inv; rd3 = e3 * inv;
          a0 = sm.d.act[4]; a1 = sm.d.act[5]; a2 = sm.d.act[6]; a3 = sm.d.act[7];
          mx = fmaxf(fmaxf(a0, a1), fmaxf(a2, a3));
          e0 = expf(a0 - mx); e1 = expf(a1 - mx); e2 = expf(a2 - mx); e3 = expf(a3 - mx);
          inv = 1.f / (e0 + e1 + e2 + e3);
          wd0 = e0 * inv; wd1 = e1 * inv; wd2 = e2 * inv; wd3 = e3 * inv;
          rw0 = 1.f / (1.f + expf(-sm.d.act[8]));
          rw1 = 1.f / (1.f + expf(-sm.d.act[9]));
        }
        const int c = tid & 63, ls = tid >> 6;
        {
          float pv = 0.f, pk = 0.f;
#pragma unroll
          for (int i = 0; i < 8; ++i) {
            int l = ls * 8 + i;
            float wp = sm.d.wpos[l];
            pv = fmaf(sm.d.tape[l][c], wp, pv);
            pk = fmaf(sm.d.tkey[l][c], wp, pk);
          }
          sm.d.scrA[tid] = pv; sm.d.scrB[tid] = pk;
        }
        __syncthreads();
        if (tid < 64) {
          float ov = sm.d.scrA[tid] + sm.d.scrA[tid + 64] + sm.d.scrA[tid + 128] + sm.d.scrA[tid + 192];
          float ok = sm.d.scrB[tid] + sm.d.scrB[tid + 64] + sm.d.scrB[tid + 128] + sm.d.scrB[tid + 192];
          sm.d.dv[tid] = (sm.d.v[tid] - ov) * rw1;
          sm.d.dk[tid] = (sm.d.kr[tid] - ok) * rw1;
        }
        __syncthreads();
        {
          float pr = 0.f;
          float dvc = sm.d.dv[c], dkc = sm.d.dk[c];
#pragma unroll
          for (int i = 0; i < 8; ++i) {
            int l = ls * 8 + i;
            float wp = sm.d.wpos[l];
            float tv = sm.d.tape[l][c] + wp * dvc;
            sm.d.tape[l][c] = tv;
            sm.d.tkey[l][c] += wp * dkc;
            pr = fmaf(tv, sm.d.rpos[l], pr);
          }
          sm.d.scrA[tid] = pr;
        }
        __syncthreads();
        if (tid < 64) {
          float r = sm.d.scrA[tid] + sm.d.scrA[tid + 64] + sm.d.scrA[tid + 128] + sm.d.scrA[tid + 192];
          sm.d.ro[tid] = r * rw0;
        }
        {
          int l2 = tid & 31, cs2 = tid >> 5;
          float pj = 0.f;
#pragma unroll
          for (int i = 0; i < 8; ++i) {
            int cc = cs2 * 8 + i;
            pj = fmaf(sm.d.tkey[l2][cc], sm.d.q[cc], pj);
          }
          sm.d.scrB[tid] = pj;
        }
        __syncthreads();
        float jp = 0.f;
        if (tid < 32) {
#pragma unroll
          for (int cs3 = 0; cs3 < 8; ++cs3) jp += sm.d.scrB[cs3 * 32 + tid];
        }
        if (tid < 64) {
          float v2 = (tid < 32) ? jp : 0.f;
          float ss = v2 * v2;
#pragma unroll
          for (int off = 32; off > 0; off >>= 1) ss += __shfl_down(ss, off, 64);
          if (tid == 0) sm.d.norm = fmaxf(sqrtf(ss), 1e-12f);
        }
        __syncthreads();
        if (tid < 32) {
          float jn = jp / sm.d.norm;
          float prv = sm.d.rpos[(tid + 1) & 31];
          float nxt = sm.d.rpos[(tid + 31) & 31];
          float rp = sm.d.rpos[tid], wp = sm.d.wpos[tid];
          float wnew = prv * wd0 + wp * wd1 + nxt * wd2 + jn * wd3;
          float rnew = prv * rd0 + rp * rd1 + nxt * rd2 + jn * rd3;
          sm.d.wpos[tid] = wnew;
          sm.d.rpos[tid] = rnew;
        }
        if (tid < 64) {
          float rov = sm.d.ro[tid];
          ws[H2_OFF + ((tau + 1) & 1) * 24576 + n * 768 + 512 + tpp * 64 + tid] = rov;
          ws[ROT_OFF + (size_t)tau * 8192 + (tpp * 64 + tid) * 32 + n] = rov;
        }
        if (tau == S_LEN - 1) {
          __syncthreads();
          for (int i = tid; i < 2048; i += 256) {
            int l = i >> 6, cc = i & 63;
            out[4194304 + (l * 32 + n) * 256 + tpp * 64 + cc] = sm.d.tape[l][cc];
          }
        }
      }
    }
    grid.sync();
  }
}

__global__ __launch_bounds__(256) void k_out_gemm(const float* __restrict__ roT, const float* __restrict__ Wo,
                                                  const float* __restrict__ bo, float* __restrict__ out) {
  int s = blockIdx.x >> 1, dh = blockIdx.x & 1;
  int d = dh * 256 + threadIdx.x;
  const float* rb = roT + (size_t)s * 8192;
  float acc[32];
#pragma unroll
  for (int n = 0; n < 32; ++n) acc[n] = 0.f;
  for (int m = 0; m < 256; ++m) {
    float w = Wo[m * 512 + d];
    const float4* rc = (const float4*)(rb + m * 32);
#pragma unroll
    for (int j = 0; j < 8; ++j) {
      float4 r4 = rc[j];
      acc[4 * j + 0] = fmaf(r4.x, w, acc[4 * j + 0]);
      acc[4 * j + 1] = fmaf(r4.y, w, acc[4 * j + 1]);
      acc[4 * j + 2] = fmaf(r4.z, w, acc[4 * j + 2]);
      acc[4 * j + 3] = fmaf(r4.w, w, acc[4 * j + 3]);
    }
  }
  float bd = bo[d];
#pragma unroll
  for (int n = 0; n < 32; ++n) out[(size_t)(s * 32 + n) * 512 + d] = acc[n] + bd;
}

extern "C" void kernel_launch(void* const* d_in, const int* in_sizes, int n_in,
                              void* d_out, int out_size, void* d_ws, size_t ws_size,
                              hipStream_t stream) {
  const float* inp = (const float*)d_in[0];
  const float* Wih = (const float*)d_in[1];
  const float* Whh = (const float*)d_in[2];
  const float* bih = (const float*)d_in[3];
  const float* bhh = (const float*)d_in[4];
  const float* Wa  = (const float*)d_in[5];
  const float* ba  = (const float*)d_in[6];
  const float* Wv  = (const float*)d_in[7];
  const float* bv  = (const float*)d_in[8];
  const float* Wk  = (const float*)d_in[9];
  const float* bk  = (const float*)d_in[10];
  const float* Wq  = (const float*)d_in[11];
  const float* bq  = (const float*)d_in[12];
  const float* Wo  = (const float*)d_in[13];
  const float* bo  = (const float*)d_in[14];
  float* ws = (float*)d_ws;
  float* out = (float*)d_out;

  // zero h / har state (ws is re-poisoned before every launch)
  hipMemsetAsync(ws + HT_OFF, 0, (size_t)(32768 + 49152) * sizeof(float), stream);
  k_transpose_w<<<dim3(40, 3), 256, 0, stream>>>(Wa, ws + WAT_OFF, 768, 40);
  k_transpose_w<<<dim3(256, 3), 256, 0, stream>>>(Wq, ws + WQT_OFF, 768, 256);
  k_pre<<<2560, 256, 0, stream>>>(inp, Wih, bih, bhh, Wv, bv, Wk, bk, ws);
  k_knorm<<<8192, 256, 0, stream>>>(ws);

  void* args[] = { (void*)&Whh, (void*)&ba, (void*)&bq, (void*)&ws, (void*)&out };
  hipLaunchCooperativeKernel((void*)nam_coop, dim3(256), dim3(256), args, 0, stream);

  k_out_gemm<<<512, 256, 0, stream>>>(ws + ROT_OFF, Wo, bo, out);
}

// Round 3
// 6109.795 us; speedup vs baseline: 2.0512x; 1.8102x over previous
//
#include <hip/hip_runtime.h>

#define S_LEN 256
// ws float offsets
#define GI_OFF   0u           // [256][2048][32]  x@Wih + bih + bhh, [s][col][n]
#define VAL_OFF  16777216u    // [256][32][256]   x@Wv + bv
#define KEY_OFF  18874368u    // [256][32][256]   unitnorm(x@Wk + bk)
#define ROT_OFF  20971520u    // [256][256][32]   read_outs transposed
#define HT_OFF   23068672u    // [2][512][32]     h double-buffered, [d][n]
#define H2_OFF   23101440u    // [2][32][768]     har rows: h(512) ++ ro(256)
#define WAT_OFF  23150592u    // [40][768]
#define WQT_OFF  23181312u    // [256][768]
#define BAR_OFF  23377920u    // barrier counter (1 u32)
#define WS_TOTAL 23377936u

// ---- agent-scope coherent helpers: bypass stale L2, hit the LLC coherence point ----
__device__ __forceinline__ float2 coh_ld2(const float* p) {
  union { unsigned long long u; float2 f; } cv;
  cv.u = __hip_atomic_load((unsigned long long*)p, __ATOMIC_RELAXED, __HIP_MEMORY_SCOPE_AGENT);
  return cv.f;
}
__device__ __forceinline__ void coh_st(float* p, float v) {
  __hip_atomic_store(p, v, __ATOMIC_RELAXED, __HIP_MEMORY_SCOPE_AGENT);
}

// Relaxed monotone grid barrier: no acquire-invalidate, no release-writeback.
// Safe because (a) __syncthreads drains vmcnt per wave before s_barrier, so all
// write-through (agent-scope) stores are at the LLC before the arrival add lands,
// and (b) consumers read cross-block data with agent-scope loads (LLC-fresh).
__device__ __forceinline__ void grid_bar(unsigned* c, int tid, unsigned tgt) {
  __syncthreads();
  if (tid == 0) {
    __hip_atomic_fetch_add(c, 1u, __ATOMIC_RELAXED, __HIP_MEMORY_SCOPE_AGENT);
    while (__hip_atomic_load(c, __ATOMIC_RELAXED, __HIP_MEMORY_SCOPE_AGENT) < tgt)
      __builtin_amdgcn_s_sleep(1);
  }
  __syncthreads();
}

__global__ __launch_bounds__(256) void k_transpose_w(const float* __restrict__ src, float* __restrict__ dst,
                                                     int K, int C) {
  int c = blockIdx.x;
  int k = blockIdx.y * 256 + threadIdx.x;
  dst[c * K + k] = src[k * C + c];
}

// ---- parallel pre-pass: gi = x@Wih + bih + bhh ; values = x@Wv+bv ; keys_raw = x@Wk+bk ----
__global__ __launch_bounds__(256) void k_pre(const float* __restrict__ inp,
    const float* __restrict__ Wih, const float* __restrict__ bih, const float* __restrict__ bhh,
    const float* __restrict__ Wv, const float* __restrict__ bv,
    const float* __restrict__ Wk, const float* __restrict__ bk, float* __restrict__ ws)
{
  __shared__ __align__(16) float xs[256 * 32];
  const int s = blockIdx.x / 10, tile = blockIdx.x % 10;
  const int tid = threadIdx.x;
  const float* W; int C, c;
  if (tile < 8)       { W = Wih; C = 2048; c = tile * 256 + tid; }
  else if (tile == 8) { W = Wv;  C = 256;  c = tid; }
  else                { W = Wk;  C = 256;  c = tid; }

  float acc[32];
#pragma unroll
  for (int n = 0; n < 32; ++n) acc[n] = 0.f;

  for (int p = 0; p < 2; ++p) {
    __syncthreads();
    for (int w = 0; w < 32; ++w) {
      int i = tid + w * 256;
      int k = i & 255, n = i >> 8;
      float v = inp[s * 16384 + n * 512 + p * 256 + k];
      int pos = ((((n >> 2) + (k & 7)) & 7) << 2) | (n & 3);
      xs[k * 32 + pos] = v;
    }
    __syncthreads();
    const float* Wp = W + (size_t)(p * 256) * C + c;
#pragma unroll 8
    for (int kk = 0; kk < 256; ++kk) {
      float wv = Wp[(size_t)kk * C];
      const float4* row = (const float4*)(xs + kk * 32);
#pragma unroll
      for (int j = 0; j < 8; ++j) {
        float4 a = row[(j + (kk & 7)) & 7];
        acc[4 * j + 0] = fmaf(a.x, wv, acc[4 * j + 0]);
        acc[4 * j + 1] = fmaf(a.y, wv, acc[4 * j + 1]);
        acc[4 * j + 2] = fmaf(a.z, wv, acc[4 * j + 2]);
        acc[4 * j + 3] = fmaf(a.w, wv, acc[4 * j + 3]);
      }
    }
  }

  if (tile < 8) {
    float bb = bih[c] + bhh[c];
    float4* dst = (float4*)(ws + GI_OFF + (size_t)s * 65536 + (size_t)c * 32);
#pragma unroll
    for (int j = 0; j < 8; ++j)
      dst[j] = make_float4(acc[4 * j] + bb, acc[4 * j + 1] + bb, acc[4 * j + 2] + bb, acc[4 * j + 3] + bb);
  } else {
    unsigned base = (tile == 8) ? VAL_OFF : KEY_OFF;
    float bb = (tile == 8) ? bv[c] : bk[c];
#pragma unroll
    for (int n = 0; n < 32; ++n)
      ws[base + (size_t)s * 8192 + n * 256 + c] = acc[n] + bb;
  }
}

__global__ __launch_bounds__(256) void k_knorm(float* __restrict__ ws) {
  int b = blockIdx.x;
  int m = threadIdx.x;
  float* p = ws + KEY_OFF + (size_t)b * 256;
  float x = p[m];
  float ss = x * x;
#pragma unroll
  for (int off = 32; off > 0; off >>= 1) ss += __shfl_xor(ss, off, 64);
  p[m] = x / fmaxf(sqrtf(ss), 1e-12f);
}

struct P1S { float hs[256 * 32]; float sg[16][33]; };
struct DS {
  float tape[32][64]; float tkey[32][64];
  float rpos[32]; float wpos[32];
  float har[768];
  float act[12]; float q[64]; float v[64]; float kr[64];
  float dv[64]; float dk[64]; float ro[64];
  float scrA[256]; float scrB[256];
  float norm;
};
union __align__(16) SU { P1S p; DS d; };

__global__ __launch_bounds__(256) void nam_coop(
    const float* __restrict__ Whh, const float* __restrict__ ba, const float* __restrict__ bq,
    float* __restrict__ ws, float* __restrict__ out)
{
  __shared__ SU sm;
  const int blk = blockIdx.x, tid = threadIdx.x;
  const bool isP1 = (blk < 128);
  unsigned* barp = (unsigned*)(ws + BAR_OFF);

  // ---- persistent-RNN preload: each LSTM thread owns 32 Whh weights in VGPRs ----
  const int ks = tid & 15, cs = tid >> 4;
  const int dd = cs & 3, g4 = cs >> 2;
  const int col = g4 * 512 + blk * 4 + dd;
  float w[32];
  float creg = 0.f;
  const int dfin = tid >> 5, nfin = tid & 31;
  if (isP1) {
#pragma unroll
    for (int kk2 = 0; kk2 < 32; ++kk2) {
      int k = (kk2 >> 4) * 256 + (kk2 & 15) * 16 + ks;
      w[kk2] = Whh[(size_t)k * 2048 + col];
    }
  } else {
    for (int i = tid; i < 2048; i += 256) { int l = i >> 6, c = i & 63; sm.d.tape[l][c] = 0.f; sm.d.tkey[l][c] = 0.f; }
    if (tid < 32) { sm.d.rpos[tid] = (tid == 0) ? 1.f : 0.f; sm.d.wpos[tid] = (tid == 0) ? 1.f : 0.f; }
    __syncthreads();
  }

  for (int t = 0; t <= S_LEN; ++t) {
    if (isP1) {
      if (t < S_LEN) {
        float gic[4] = {0.f, 0.f, 0.f, 0.f};
        if (tid < 128) {
#pragma unroll
          for (int g = 0; g < 4; ++g)
            gic[g] = ws[GI_OFF + (size_t)t * 65536 + (size_t)(g * 512 + blk * 4 + dfin) * 32 + nfin];
        }
        float acc[32];
#pragma unroll
        for (int n = 0; n < 32; ++n) acc[n] = 0.f;
        const float* hsrc = ws + HT_OFF + ((t + 1) & 1) * 16384;
        for (int p = 0; p < 2; ++p) {
          __syncthreads();
          // stage 256 rows of h [k][n] into LDS via agent-scope (LLC-fresh) 8B loads
          const float2* src2 = (const float2*)(hsrc + p * 8192);
          float2* dst2 = (float2*)sm.p.hs;
#pragma unroll
          for (int w2 = 0; w2 < 16; ++w2) {
            int i2 = tid + w2 * 256;
            float2 v = coh_ld2((const float*)(src2 + i2));
            int r = i2 >> 4, j2 = i2 & 15;
            int pos = (((j2 >> 1) ^ (r & 7)) << 1) | (j2 & 1);
            dst2[r * 16 + pos] = v;
          }
          __syncthreads();
#pragma unroll
          for (int kk = 0; kk < 16; ++kk) {
            int r = kk * 16 + ks;
            float wv = w[p * 16 + kk];
            const float4* row = (const float4*)sm.p.hs + r * 8;
#pragma unroll
            for (int j = 0; j < 8; ++j) {
              float4 a = row[j ^ (r & 7)];
              acc[4 * j + 0] = fmaf(a.x, wv, acc[4 * j + 0]);
              acc[4 * j + 1] = fmaf(a.y, wv, acc[4 * j + 1]);
              acc[4 * j + 2] = fmaf(a.z, wv, acc[4 * j + 2]);
              acc[4 * j + 3] = fmaf(a.w, wv, acc[4 * j + 3]);
            }
          }
        }
#pragma unroll
        for (int n = 0; n < 32; ++n) {
          float v = acc[n];
          v += __shfl_down(v, 8, 16);
          v += __shfl_down(v, 4, 16);
          v += __shfl_down(v, 2, 16);
          v += __shfl_down(v, 1, 16);
          acc[n] = v;
        }
        if (ks == 0) {
#pragma unroll
          for (int n = 0; n < 32; ++n) sm.p.sg[cs][n] = acc[n];
        }
        __syncthreads();
        if (tid < 128) {
          float gv[4];
#pragma unroll
          for (int g = 0; g < 4; ++g) gv[g] = sm.p.sg[g * 4 + dfin][nfin] + gic[g];
          float si = 1.f / (1.f + expf(-gv[0]));
          float sf = 1.f / (1.f + expf(-gv[1]));
          float so = 1.f / (1.f + expf(-gv[3]));
          float cn = sf * creg + si * tanhf(gv[2]);
          float hn = so * tanhf(cn);
          creg = cn;
          int dg = blk * 4 + dfin;
          coh_st(ws + HT_OFF + (t & 1) * 16384 + dg * 32 + nfin, hn);
          coh_st(ws + H2_OFF + (t & 1) * 24576 + nfin * 768 + dg, hn);
        }
      }
    } else {
      if (t >= 1) {
        const int tau = t - 1;
        const int gidx = blk - 128, n = gidx >> 2;
        const int tpp = gidx & 3;
        {
          const float2* hrow2 = (const float2*)(ws + H2_OFF + (tau & 1) * 24576 + n * 768);
          if (tid < 192) {
            float2 a = coh_ld2((const float*)(hrow2 + 2 * tid));
            float2 b = coh_ld2((const float*)(hrow2 + 2 * tid + 1));
            ((float2*)sm.d.har)[2 * tid] = a;
            ((float2*)sm.d.har)[2 * tid + 1] = b;
          }
          if (tid < 64)       sm.d.v[tid]       = ws[VAL_OFF + (size_t)tau * 8192 + n * 256 + tpp * 64 + tid];
          else if (tid < 128) sm.d.kr[tid - 64] = ws[KEY_OFF + (size_t)tau * 8192 + n * 256 + tpp * 64 + (tid - 64)];
        }
        __syncthreads();
        // action (10) + query (64), K=768, 3-way K-split; weights stay L2-resident now
        if (tid < 222) {
          int o = tid % 74, ks2 = tid / 74;
          const float* wt = (o < 10) ? (ws + WAT_OFF + (tpp * 10 + o) * 768)
                                     : (ws + WQT_OFF + (tpp * 64 + (o - 10)) * 768);
          const float4* w4 = (const float4*)(wt + ks2 * 256);
          const float4* h4 = (const float4*)(sm.d.har + ks2 * 256);
          float p = 0.f;
#pragma unroll 16
          for (int j = 0; j < 64; ++j) {
            float4 a = w4[j], b = h4[j];
            p += a.x * b.x + a.y * b.y + a.z * b.z + a.w * b.w;
          }
          sm.d.scrA[tid] = p;
        }
        __syncthreads();
        if (tid < 74) {
          float val = sm.d.scrA[tid] + sm.d.scrA[tid + 74] + sm.d.scrA[tid + 148];
          if (tid < 10) sm.d.act[tid] = val + ba[tpp * 10 + tid];
          else          sm.d.q[tid - 10] = val + bq[tpp * 64 + tid - 10];
        }
        __syncthreads();
        float rd0, rd1, rd2, rd3, wd0, wd1, wd2, wd3, rw0, rw1;
        {
          float a0 = sm.d.act[0], a1 = sm.d.act[1], a2 = sm.d.act[2], a3 = sm.d.act[3];
          float mx = fmaxf(fmaxf(a0, a1), fmaxf(a2, a3));
          float e0 = expf(a0 - mx), e1 = expf(a1 - mx), e2 = expf(a2 - mx), e3 = expf(a3 - mx);
          float inv = 1.f / (e0 + e1 + e2 + e3);
          rd0 = e0 * inv; rd1 = e1 * inv; rd2 = e2 * inv; rd3 = e3 * inv;
          a0 = sm.d.act[4]; a1 = sm.d.act[5]; a2 = sm.d.act[6]; a3 = sm.d.act[7];
          mx = fmaxf(fmaxf(a0, a1), fmaxf(a2, a3));
          e0 = expf(a0 - mx); e1 = expf(a1 - mx); e2 = expf(a2 - mx); e3 = expf(a3 - mx);
          inv = 1.f / (e0 + e1 + e2 + e3);
          wd0 = e0 * inv; wd1 = e1 * inv; wd2 = e2 * inv; wd3 = e3 * inv;
          rw0 = 1.f / (1.f + expf(-sm.d.act[8]));
          rw1 = 1.f / (1.f + expf(-sm.d.act[9]));
        }
        const int c = tid & 63, ls = tid >> 6;
        {
          float pv = 0.f, pk = 0.f;
#pragma unroll
          for (int i = 0; i < 8; ++i) {
            int l = ls * 8 + i;
            float wp = sm.d.wpos[l];
            pv = fmaf(sm.d.tape[l][c], wp, pv);
            pk = fmaf(sm.d.tkey[l][c], wp, pk);
          }
          sm.d.scrA[tid] = pv; sm.d.scrB[tid] = pk;
        }
        __syncthreads();
        if (tid < 64) {
          float ov = sm.d.scrA[tid] + sm.d.scrA[tid + 64] + sm.d.scrA[tid + 128] + sm.d.scrA[tid + 192];
          float ok = sm.d.scrB[tid] + sm.d.scrB[tid + 64] + sm.d.scrB[tid + 128] + sm.d.scrB[tid + 192];
          sm.d.dv[tid] = (sm.d.v[tid] - ov) * rw1;
          sm.d.dk[tid] = (sm.d.kr[tid] - ok) * rw1;
        }
        __syncthreads();
        {
          float pr = 0.f;
          float dvc = sm.d.dv[c], dkc = sm.d.dk[c];
#pragma unroll
          for (int i = 0; i < 8; ++i) {
            int l = ls * 8 + i;
            float wp = sm.d.wpos[l];
            float tv = sm.d.tape[l][c] + wp * dvc;
            sm.d.tape[l][c] = tv;
            sm.d.tkey[l][c] += wp * dkc;
            pr = fmaf(tv, sm.d.rpos[l], pr);
          }
          sm.d.scrA[tid] = pr;
        }
        __syncthreads();
        if (tid < 64) {
          float r = sm.d.scrA[tid] + sm.d.scrA[tid + 64] + sm.d.scrA[tid + 128] + sm.d.scrA[tid + 192];
          sm.d.ro[tid] = r * rw0;
        }
        {
          int l2 = tid & 31, cs2 = tid >> 5;
          float pj = 0.f;
#pragma unroll
          for (int i = 0; i < 8; ++i) {
            int cc = cs2 * 8 + i;
            pj = fmaf(sm.d.tkey[l2][cc], sm.d.q[cc], pj);
          }
          sm.d.scrB[tid] = pj;
        }
        __syncthreads();
        float jp = 0.f;
        if (tid < 32) {
#pragma unroll
          for (int cs3 = 0; cs3 < 8; ++cs3) jp += sm.d.scrB[cs3 * 32 + tid];
        }
        if (tid < 64) {
          float v2 = (tid < 32) ? jp : 0.f;
          float ss = v2 * v2;
#pragma unroll
          for (int off = 32; off > 0; off >>= 1) ss += __shfl_down(ss, off, 64);
          if (tid == 0) sm.d.norm = fmaxf(sqrtf(ss), 1e-12f);
        }
        __syncthreads();
        if (tid < 32) {
          float jn = jp / sm.d.norm;
          float prv = sm.d.rpos[(tid + 1) & 31];
          float nxt = sm.d.rpos[(tid + 31) & 31];
          float rp = sm.d.rpos[tid], wp = sm.d.wpos[tid];
          float wnew = prv * wd0 + wp * wd1 + nxt * wd2 + jn * wd3;
          float rnew = prv * rd0 + rp * rd1 + nxt * rd2 + jn * rd3;
          sm.d.wpos[tid] = wnew;
          sm.d.rpos[tid] = rnew;
        }
        if (tid < 64) {
          float rov = sm.d.ro[tid];
          coh_st(ws + H2_OFF + ((tau + 1) & 1) * 24576 + n * 768 + 512 + tpp * 64 + tid, rov);
          ws[ROT_OFF + (size_t)tau * 8192 + (tpp * 64 + tid) * 32 + n] = rov;
        }
        if (tau == S_LEN - 1) {
          __syncthreads();
          for (int i = tid; i < 2048; i += 256) {
            int l = i >> 6, cc = i & 63;
            out[4194304 + (l * 32 + n) * 256 + tpp * 64 + cc] = sm.d.tape[l][cc];
          }
        }
      }
    }
    if (t < S_LEN) grid_bar(barp, tid, 256u * (unsigned)(t + 1));
  }
}

__global__ __launch_bounds__(256) void k_out_gemm(const float* __restrict__ roT, const float* __restrict__ Wo,
                                                  const float* __restrict__ bo, float* __restrict__ out) {
  int s = blockIdx.x >> 1, dh = blockIdx.x & 1;
  int d = dh * 256 + threadIdx.x;
  const float* rb = roT + (size_t)s * 8192;
  float acc[32];
#pragma unroll
  for (int n = 0; n < 32; ++n) acc[n] = 0.f;
  for (int m = 0; m < 256; ++m) {
    float w = Wo[m * 512 + d];
    const float4* rc = (const float4*)(rb + m * 32);
#pragma unroll
    for (int j = 0; j < 8; ++j) {
      float4 r4 = rc[j];
      acc[4 * j + 0] = fmaf(r4.x, w, acc[4 * j + 0]);
      acc[4 * j + 1] = fmaf(r4.y, w, acc[4 * j + 1]);
      acc[4 * j + 2] = fmaf(r4.z, w, acc[4 * j + 2]);
      acc[4 * j + 3] = fmaf(r4.w, w, acc[4 * j + 3]);
    }
  }
  float bd = bo[d];
#pragma unroll
  for (int n = 0; n < 32; ++n) out[(size_t)(s * 32 + n) * 512 + d] = acc[n] + bd;
}

extern "C" void kernel_launch(void* const* d_in, const int* in_sizes, int n_in,
                              void* d_out, int out_size, void* d_ws, size_t ws_size,
                              hipStream_t stream) {
  const float* inp = (const float*)d_in[0];
  const float* Wih = (const float*)d_in[1];
  const float* Whh = (const float*)d_in[2];
  const float* bih = (const float*)d_in[3];
  const float* bhh = (const float*)d_in[4];
  const float* Wa  = (const float*)d_in[5];
  const float* ba  = (const float*)d_in[6];
  const float* Wv  = (const float*)d_in[7];
  const float* bv  = (const float*)d_in[8];
  const float* Wk  = (const float*)d_in[9];
  const float* bk  = (const float*)d_in[10];
  const float* Wq  = (const float*)d_in[11];
  const float* bq  = (const float*)d_in[12];
  const float* Wo  = (const float*)d_in[13];
  const float* bo  = (const float*)d_in[14];
  float* ws = (float*)d_ws;
  float* out = (float*)d_out;

  hipMemsetAsync(ws + HT_OFF, 0, (size_t)(32768 + 49152) * sizeof(float), stream);
  hipMemsetAsync(ws + BAR_OFF, 0, sizeof(unsigned), stream);
  k_transpose_w<<<dim3(40, 3), 256, 0, stream>>>(Wa, ws + WAT_OFF, 768, 40);
  k_transpose_w<<<dim3(256, 3), 256, 0, stream>>>(Wq, ws + WQT_OFF, 768, 256);
  k_pre<<<2560, 256, 0, stream>>>(inp, Wih, bih, bhh, Wv, bv, Wk, bk, ws);
  k_knorm<<<8192, 256, 0, stream>>>(ws);

  void* args[] = { (void*)&Whh, (void*)&ba, (void*)&bq, (void*)&ws, (void*)&out };
  hipLaunchCooperativeKernel((void*)nam_coop, dim3(256), dim3(256), args, 0, stream);

  k_out_gemm<<<512, 256, 0, stream>>>(ws + ROT_OFF, Wo, bo, out);
}